// Round 4
// baseline (220.410 us; speedup 1.0000x reference)
//
#include <hip/hip_runtime.h>
#include <hip/hip_bf16.h>

#define NF 50
#define NCARD 10000
#define FD 64
#define NPAIR 1225        // 50*49/2
#define NPAIR_PAD 1232    // 77*16
#define NTILE 77
#define NB 2              // batch elements per block (one per wave-pair)
#define FROWB 144         // bytes per field row in LDS (72 f16, non-pow2 -> 2-way max)
#define FBATB 7200        // bytes per batch section (50*144)

typedef _Float16 h16x8 __attribute__((ext_vector_type(8)));
typedef float f32x4 __attribute__((ext_vector_type(4)));

// ---------------- pre-kernel: batch-invariant tables into d_ws ----------------
// ws layout: [0,8192) f16 W1 fragments, slot-major: frag[(mt*2+ks)*64 + lane][8]
//            [8192, 8192+4*NPAIR_PAD) unsigned poff: fi*144 | (fj*144 << 16)
__global__ void afm_pre(const float* __restrict__ W1,
                        _Float16* __restrict__ w1f,
                        unsigned* __restrict__ poffg) {
    const int bid = blockIdx.x, tid = threadIdx.x;
    if (bid < 2) {
        const int slot = bid * 4 + (tid >> 6);   // 0..7 = mt*2+ks
        const int lane = tid & 63;
        const int n16 = lane & 15, quad = lane >> 4;
        const int mt = slot >> 1, ks = slot & 1;
        const int a = mt * 16 + n16;
        h16x8 v;
        #pragma unroll
        for (int jj = 0; jj < 8; ++jj) {
            int k = ks * 32 + quad * 8 + jj;
            v[jj] = (_Float16)W1[k * 64 + a];    // A[m=a][k] = W1^T
        }
        *(h16x8*)(w1f + ((size_t)(slot * 64 + lane)) * 8) = v;
    } else {
        int p = (bid - 2) * 256 + tid;
        if (p < NPAIR_PAD) {
            int i = 0, j = 0;
            if (p < NPAIR) {
                float disc = (float)((2 * NF - 1) * (2 * NF - 1) - 8 * p);
                i = (int)(((float)(2 * NF - 1) - sqrtf(disc)) * 0.5f);
                if (i < 0) i = 0;
                if (i > NF - 2) i = NF - 2;
                while (i + 1 <= NF - 2 && (i + 1) * (NF - 1) - ((i + 1) * i) / 2 <= p) ++i;
                while (i > 0 && i * (NF - 1) - (i * (i - 1)) / 2 > p) --i;
                j = p - (i * (NF - 1) - (i * (i - 1)) / 2) + i + 1;
            }
            poffg[p] = (unsigned)(i * FROWB) | ((unsigned)(j * FROWB) << 16);
        }
    }
}

// ---------------- main kernel: 2 batches/block, online softmax in regs --------
// NOTE: no min-waves in launch_bounds — R3's (256,4) capped VGPR at 128 and
// (theory) forced in-loop scratch spills. Keep live set small instead.
__global__ __launch_bounds__(256) void afm_main(
    const int* __restrict__ x,
    const float* __restrict__ emb,
    const float* __restrict__ b1,
    const float* __restrict__ w2,
    const float* __restrict__ lin_w,
    const float* __restrict__ lin_b,
    const _Float16* __restrict__ w1f,
    const unsigned* __restrict__ poffg,
    float* __restrict__ out)
{
    __shared__ __align__(16) _Float16 fach[NB * 50 * 72]; // 14400 B
    __shared__ float cmb[4][3];

    const int b0   = blockIdx.x * NB;
    const int tid  = threadIdx.x;
    const int lane = tid & 63;
    const int wid  = tid >> 6;
    const int n16  = lane & 15;
    const int quad = lane >> 4;

    // ---- stage NB*50 factor rows as f16 (coalesced float4 loads) ----
    for (int t = tid; t < NB * 50 * 8; t += 256) {
        int rowid = t >> 3, q = t & 7;
        int bb = (rowid >= 50) ? 1 : 0;
        int f = rowid - bb * 50;
        int gid = x[(b0 + bb) * NF + f] + f * NCARD;
        const float* src = emb + (size_t)gid * FD + q * 8;
        float4 v0 = *(const float4*)(src);
        float4 v1 = *(const float4*)(src + 4);
        h16x8 h;
        h[0] = (_Float16)v0.x; h[1] = (_Float16)v0.y;
        h[2] = (_Float16)v0.z; h[3] = (_Float16)v0.w;
        h[4] = (_Float16)v1.x; h[5] = (_Float16)v1.y;
        h[6] = (_Float16)v1.z; h[7] = (_Float16)v1.w;
        *(h16x8*)(fach + bb * 3600 + f * 72 + q * 8) = h;
    }

    // ---- per-lane constants (register-resident) ----
    h16x8 afragW[8];                       // W1^T fragments, [mt*2+ks]  (32 VGPR)
    #pragma unroll
    for (int s = 0; s < 8; ++s)
        afragW[s] = *(const h16x8*)(w1f + ((size_t)(s * 64 + lane)) * 8);
    h16x8 aones;                           // virtual ones-row tile -> inter_sum
    {
        _Float16 o = (n16 == 0) ? (_Float16)1.0f : (_Float16)0.0f;
        #pragma unroll
        for (int jj = 0; jj < 8; ++jj) aones[jj] = o;
    }
    f32x4 b1v[4], w2v[4];                  // C row = mt*16 + quad*4 + r  (32 VGPR)
    #pragma unroll
    for (int mt = 0; mt < 4; ++mt) {
        const float4 bb = *(const float4*)(b1 + mt * 16 + quad * 4);
        const float4 ww = *(const float4*)(w2 + mt * 16 + quad * 4);
        b1v[mt] = (f32x4){bb.x, bb.y, bb.z, bb.w};
        w2v[mt] = (f32x4){ww.x, ww.y, ww.z, ww.w};
    }
    __syncthreads();

    // ---- main loop: wave pair (2w, 2w+1) covers batch w; online softmax ----
    const int mybatch = wid >> 1;
    const char* fb = (const char*)fach + mybatch * FBATB;
    float m = -1e30f, se = 0.f, sei = 0.f;

    for (int t = (wid & 1); t < NTILE; t += 2) {
        const unsigned po = poffg[t * 16 + n16];   // 4.9 KB table, L1-hot
        const char* pbi = fb + (po & 0xFFFFu) + quad * 16;
        const char* pbj = fb + (po >> 16) + quad * 16;

        h16x8 pr0 = (*(const h16x8*)(pbi)) * (*(const h16x8*)(pbj));
        h16x8 pr1 = (*(const h16x8*)(pbi + 64)) * (*(const h16x8*)(pbj + 64));

        f32x4 accS = __builtin_amdgcn_mfma_f32_16x16x32_f16(aones, pr0, (f32x4){0.f, 0.f, 0.f, 0.f}, 0, 0, 0);
        accS = __builtin_amdgcn_mfma_f32_16x16x32_f16(aones, pr1, accS, 0, 0, 0);

        float lacc = 0.f;                          // sum_a relu(h)*w2, rows in-lane
        #pragma unroll
        for (int mt = 0; mt < 4; ++mt) {           // only ONE acc tile live at a time
            f32x4 acc = __builtin_amdgcn_mfma_f32_16x16x32_f16(afragW[mt * 2 + 0], pr0, b1v[mt], 0, 0, 0);
            acc = __builtin_amdgcn_mfma_f32_16x16x32_f16(afragW[mt * 2 + 1], pr1, acc, 0, 0, 0);
            #pragma unroll
            for (int r = 0; r < 4; ++r)
                lacc += fmaxf(acc[r], 0.f) * w2v[mt][r];
        }
        lacc += __shfl_xor(lacc, 16, 64);          // reduce over att rows
        lacc += __shfl_xor(lacc, 32, 64);
        float is = __shfl(accS[0], n16, 64);       // inter_sum lives in quad-0 row 0

        if (t * 16 + n16 >= NPAIR) lacc = -1e30f;  // padded pairs (tile 76 only)

        float nm = fmaxf(m, lacc);
        float sc = __expf(m - nm);
        float e  = __expf(lacc - nm);
        se  = se * sc + e;
        sei = sei * sc + e * is;
        m = nm;
    }

    // merge per-lane online states across the 16 pair-residues (quads replicated)
    #pragma unroll
    for (int d = 1; d <= 8; d <<= 1) {
        float m2   = __shfl_xor(m, d, 64);
        float se2  = __shfl_xor(se, d, 64);
        float sei2 = __shfl_xor(sei, d, 64);
        float nm = fmaxf(m, m2);
        float a = __expf(m - nm), bsc = __expf(m2 - nm);
        se  = se * a + se2 * bsc;
        sei = sei * a + sei2 * bsc;
        m = nm;
    }

    // linear term: even wave of each pair gathers lin_w
    float lin = 0.f;
    if ((wid & 1) == 0) {
        if (lane < NF) {
            int gid = x[(b0 + mybatch) * NF + lane] + lane * NCARD;
            lin = lin_w[gid];
        }
        #pragma unroll
        for (int d = 1; d <= 32; d <<= 1) lin += __shfl_xor(lin, d, 64);
    }

    // cross-wave combine (one barrier) + output
    if (lane == 0) { cmb[wid][0] = m; cmb[wid][1] = se; cmb[wid][2] = sei; }
    __syncthreads();
    if ((wid & 1) == 0 && lane == 0) {
        float m2 = cmb[wid + 1][0], se2 = cmb[wid + 1][1], sei2 = cmb[wid + 1][2];
        float nm = fmaxf(m, m2);
        float a = __expf(m - nm), bsc = __expf(m2 - nm);
        float tse  = se * a + se2 * bsc;
        float tsei = sei * a + sei2 * bsc;
        out[b0 + mybatch] = lin + lin_b[0] + tsei / tse;
    }
}

extern "C" void kernel_launch(void* const* d_in, const int* in_sizes, int n_in,
                              void* d_out, int out_size, void* d_ws, size_t ws_size,
                              hipStream_t stream) {
    const int*   x     = (const int*)d_in[0];
    const float* emb   = (const float*)d_in[1];
    const float* W1    = (const float*)d_in[2];
    const float* b1    = (const float*)d_in[3];
    const float* w2    = (const float*)d_in[4];
    // d_in[5] = b2 : constant shift on logits, cancels in softmax
    const float* lin_w = (const float*)d_in[6];
    const float* lin_b = (const float*)d_in[7];
    float* out = (float*)d_out;

    _Float16* w1f   = (_Float16*)d_ws;
    unsigned* poffg = (unsigned*)((char*)d_ws + 8192);

    afm_pre<<<7, 256, 0, stream>>>(W1, w1f, poffg);   // blocks 0-1: W1, 2-6: pairs
    const int batch = out_size; // 2048
    afm_main<<<batch / NB, 256, 0, stream>>>(x, emb, b1, w2, lin_w, lin_b, w1f, poffg, out);
}

// Round 5
// 217.150 us; speedup vs baseline: 1.0150x; 1.0150x over previous
//
#include <hip/hip_runtime.h>
#include <hip/hip_bf16.h>

#define NF 50
#define NFP 52            // fields padded to 13 groups of 4
#define NG 13
#define NCARD 10000
#define FD 64
#define NB 2              // batch elements per block (one per wave-pair)
#define FROW 72           // f16 per LDS row (144 B stride: 4-row groups spread banks, <=2-way)
#define FBAT (NFP * FROW) // f16 per batch section = 3744

typedef _Float16 h16x8 __attribute__((ext_vector_type(8)));
typedef float f32x4 __attribute__((ext_vector_type(4)));

// Single kernel: pair space tiled as 4x4 field-group blocks.
// i-rows register-cached per gi; j-rows streamed (2 ds_read_b128/tile).
__global__ __launch_bounds__(256, 4) void afm_main(
    const int* __restrict__ x,
    const float* __restrict__ emb,
    const float* __restrict__ W1,
    const float* __restrict__ b1,
    const float* __restrict__ w2,
    const float* __restrict__ lin_w,
    const float* __restrict__ lin_b,
    float* __restrict__ out)
{
    __shared__ __align__(16) _Float16 fach[NB * FBAT]; // 14976 B
    __shared__ float cmb[4][3];

    const int b0   = blockIdx.x * NB;
    const int tid  = threadIdx.x;
    const int lane = tid & 63;
    const int wid  = tid >> 6;
    const int n16  = lane & 15;
    const int quad = lane >> 4;

    // ---- stage NB*52 factor rows as f16 (rows >= NF are zeros) ----
    for (int t = tid; t < NB * NFP * 8; t += 256) {
        int rowid = t >> 3, q = t & 7;
        int bb = (rowid >= NFP) ? 1 : 0;
        int f = rowid - bb * NFP;
        h16x8 h = {0, 0, 0, 0, 0, 0, 0, 0};
        if (f < NF) {
            int gid = x[(b0 + bb) * NF + f] + f * NCARD;
            const float* src = emb + (size_t)gid * FD + q * 8;
            float4 v0 = *(const float4*)(src);
            float4 v1 = *(const float4*)(src + 4);
            h[0] = (_Float16)v0.x; h[1] = (_Float16)v0.y;
            h[2] = (_Float16)v0.z; h[3] = (_Float16)v0.w;
            h[4] = (_Float16)v1.x; h[5] = (_Float16)v1.y;
            h[6] = (_Float16)v1.z; h[7] = (_Float16)v1.w;
        }
        *(h16x8*)(fach + (size_t)rowid * FROW + q * 8) = h;
    }

    // ---- W1^T A-fragments built in-kernel (16 KB W1 is L1/L2-hot across blocks) ----
    h16x8 afragW[8];                       // [mt*2+ks]; A[m=mt*16+n16][k=ks*32+quad*8+jj]
    #pragma unroll
    for (int mt = 0; mt < 4; ++mt) {
        #pragma unroll
        for (int ks = 0; ks < 2; ++ks) {
            h16x8 v;
            #pragma unroll
            for (int jj = 0; jj < 8; ++jj)
                v[jj] = (_Float16)W1[(ks * 32 + quad * 8 + jj) * 64 + mt * 16 + n16];
            afragW[mt * 2 + ks] = v;
        }
    }
    h16x8 aones = {(_Float16)1, (_Float16)1, (_Float16)1, (_Float16)1,
                   (_Float16)1, (_Float16)1, (_Float16)1, (_Float16)1};
    // every C[m][n] of the ones-MFMA = sum_k B[k][n] = inter_sum(pair n16), all lanes
    f32x4 b1v[4], w2v[4];                  // C row = mt*16 + quad*4 + r
    #pragma unroll
    for (int mt = 0; mt < 4; ++mt) {
        const float4 bb = *(const float4*)(b1 + mt * 16 + quad * 4);
        const float4 ww = *(const float4*)(w2 + mt * 16 + quad * 4);
        b1v[mt] = (f32x4){bb.x, bb.y, bb.z, bb.w};
        w2v[mt] = (f32x4){ww.x, ww.y, ww.z, ww.w};
    }
    __syncthreads();

    // ---- main loop: wave pair covers one batch; gi groups split across the pair ----
    const int mybatch = wid >> 1;
    const _Float16* fb = fach + mybatch * FBAT;
    const int a4 = n16 >> 2, b4 = n16 & 3;
    const int gi_lo = (wid & 1) ? 4 : 0;           // 46 vs 45 tiles — balanced
    const int gi_hi = (wid & 1) ? NG : 4;

    float m = -1e30f, se = 0.f, sei = 0.f;

    for (int gi = gi_lo; gi < gi_hi; ++gi) {
        const int i = gi * 4 + a4;
        const _Float16* ri = fb + (size_t)i * FROW + quad * 8;
        const h16x8 ri0 = *(const h16x8*)(ri);       // i-row cached in regs for all gj
        const h16x8 ri1 = *(const h16x8*)(ri + 32);
        for (int gj = gi; gj < NG; ++gj) {
            const int j = gj * 4 + b4;
            const _Float16* rj = fb + (size_t)j * FROW + quad * 8;
            h16x8 pr0 = ri0 * (*(const h16x8*)(rj));        // 2 ds_read_b128 + 8 pk_mul
            h16x8 pr1 = ri1 * (*(const h16x8*)(rj + 32));

            f32x4 accS = __builtin_amdgcn_mfma_f32_16x16x32_f16(aones, pr0, (f32x4){0.f, 0.f, 0.f, 0.f}, 0, 0, 0);
            accS = __builtin_amdgcn_mfma_f32_16x16x32_f16(aones, pr1, accS, 0, 0, 0);

            float lacc = 0.f;
            #pragma unroll
            for (int mt = 0; mt < 4; ++mt) {       // one acc tile live at a time
                f32x4 acc = __builtin_amdgcn_mfma_f32_16x16x32_f16(afragW[mt * 2 + 0], pr0, b1v[mt], 0, 0, 0);
                acc = __builtin_amdgcn_mfma_f32_16x16x32_f16(afragW[mt * 2 + 1], pr1, acc, 0, 0, 0);
                #pragma unroll
                for (int r = 0; r < 4; ++r)
                    lacc += fmaxf(acc[r], 0.f) * w2v[mt][r];
            }
            lacc += __shfl_xor(lacc, 16, 64);       // att rows live across quads
            lacc += __shfl_xor(lacc, 32, 64);

            const bool valid = (i < j) && (j < NF);
            float nm = fmaxf(m, valid ? lacc : -1e30f);
            float sc = __expf(m - nm);
            float e  = valid ? __expf(lacc - nm) : 0.f;  // masked lanes contribute nothing
            se  = se * sc + e;
            sei = sei * sc + e * accS[0];
            m = nm;
        }
    }

    // merge per-lane online states across the 16 pair-residues (quads hold duplicates)
    #pragma unroll
    for (int d = 1; d <= 8; d <<= 1) {
        float m2   = __shfl_xor(m, d, 64);
        float se2  = __shfl_xor(se, d, 64);
        float sei2 = __shfl_xor(sei, d, 64);
        float nm = fmaxf(m, m2);
        float a = __expf(m - nm), bsc = __expf(m2 - nm);
        se  = se * a + se2 * bsc;
        sei = sei * a + sei2 * bsc;
        m = nm;
    }

    // linear term: even wave of each pair gathers lin_w
    float lin = 0.f;
    if ((wid & 1) == 0) {
        if (lane < NF) {
            int gid = x[(b0 + mybatch) * NF + lane] + lane * NCARD;
            lin = lin_w[gid];
        }
        #pragma unroll
        for (int d = 1; d <= 32; d <<= 1) lin += __shfl_xor(lin, d, 64);
    }

    // cross-wave combine (one barrier) + output
    if (lane == 0) { cmb[wid][0] = m; cmb[wid][1] = se; cmb[wid][2] = sei; }
    __syncthreads();
    if ((wid & 1) == 0 && lane == 0) {
        float m2 = cmb[wid + 1][0], se2 = cmb[wid + 1][1], sei2 = cmb[wid + 1][2];
        float nm = fmaxf(m, m2);
        float a = __expf(m - nm), bsc = __expf(m2 - nm);
        float tse  = se * a + se2 * bsc;
        float tsei = sei * a + sei2 * bsc;
        out[b0 + mybatch] = lin + lin_b[0] + tsei / tse;
    }
}

extern "C" void kernel_launch(void* const* d_in, const int* in_sizes, int n_in,
                              void* d_out, int out_size, void* d_ws, size_t ws_size,
                              hipStream_t stream) {
    const int*   x     = (const int*)d_in[0];
    const float* emb   = (const float*)d_in[1];
    const float* W1    = (const float*)d_in[2];
    const float* b1    = (const float*)d_in[3];
    const float* w2    = (const float*)d_in[4];
    // d_in[5] = b2 : constant shift on logits, cancels in softmax
    const float* lin_w = (const float*)d_in[6];
    const float* lin_b = (const float*)d_in[7];
    float* out = (float*)d_out;
    const int batch = out_size; // 2048
    afm_main<<<batch / NB, 256, 0, stream>>>(x, emb, W1, b1, w2, lin_w, lin_b, out);
}

// Round 6
// 216.562 us; speedup vs baseline: 1.0178x; 1.0027x over previous
//
#include <hip/hip_runtime.h>
#include <hip/hip_bf16.h>

#define NF 50
#define NFP 52            // fields padded to 13 groups of 4
#define NG 13
#define NCARD 10000
#define FD 64
#define FROW 72           // f16 per LDS row (144 B stride)

typedef _Float16 h16x8 __attribute__((ext_vector_type(8)));
typedef float f32x4 __attribute__((ext_vector_type(4)));

// ---- pre-kernel: pack W1^T MFMA A-fragments into d_ws (8 slots x 64 lanes x 16B) ----
__global__ void afm_pre(const float* __restrict__ W1, _Float16* __restrict__ w1f) {
    const int slot = blockIdx.x * 4 + (threadIdx.x >> 6);   // 0..7 = mt*2+ks
    const int lane = threadIdx.x & 63;
    const int n16 = lane & 15, quad = lane >> 4;
    const int mt = slot >> 1, ks = slot & 1;
    h16x8 v;
    #pragma unroll
    for (int jj = 0; jj < 8; ++jj)
        v[jj] = (_Float16)W1[(ks * 32 + quad * 8 + jj) * 64 + mt * 16 + n16];
    *(h16x8*)(w1f + ((size_t)(slot * 64 + lane)) * 8) = v;
}

// ---- main: 1 batch/block, 4 waves, interleaved-gi 4x4 group tiles, no-max softmax ----
__global__ __launch_bounds__(256, 4) void afm_main(
    const int* __restrict__ x,
    const float* __restrict__ emb,
    const float* __restrict__ b1,
    const float* __restrict__ w2,
    const float* __restrict__ lin_w,
    const float* __restrict__ lin_b,
    const _Float16* __restrict__ w1f,
    float* __restrict__ out)
{
    __shared__ __align__(16) _Float16 fach[NFP * FROW]; // 7488 B
    __shared__ float cmb[4][2];
    __shared__ float s_lin;

    const int b    = blockIdx.x;
    const int tid  = threadIdx.x;
    const int lane = tid & 63;
    const int wid  = tid >> 6;
    const int n16  = lane & 15;
    const int quad = lane >> 4;

    // ---- wave 3: issue scattered lin_w gather NOW; reduce after main loop ----
    float linv = 0.f;
    if (wid == 3 && lane < NF)
        linv = lin_w[x[b * NF + lane] + lane * NCARD];

    // ---- stage 52 factor rows as f16 (rows >= NF zero) ----
    for (int t = tid; t < NFP * 8; t += 256) {
        int f = t >> 3, q = t & 7;
        h16x8 h = {0, 0, 0, 0, 0, 0, 0, 0};
        if (f < NF) {
            int gid = x[b * NF + f] + f * NCARD;
            const float* src = emb + (size_t)gid * FD + q * 8;
            float4 v0 = *(const float4*)(src);
            float4 v1 = *(const float4*)(src + 4);
            h[0] = (_Float16)v0.x; h[1] = (_Float16)v0.y;
            h[2] = (_Float16)v0.z; h[3] = (_Float16)v0.w;
            h[4] = (_Float16)v1.x; h[5] = (_Float16)v1.y;
            h[6] = (_Float16)v1.z; h[7] = (_Float16)v1.w;
        }
        *(h16x8*)(fach + (size_t)f * FROW + q * 8) = h;
    }

    // ---- per-lane constants ----
    h16x8 afragW[8];                       // pre-packed W1^T fragments [mt*2+ks]
    #pragma unroll
    for (int s = 0; s < 8; ++s)
        afragW[s] = *(const h16x8*)(w1f + ((size_t)(s * 64 + lane)) * 8);
    h16x8 aones = {(_Float16)1, (_Float16)1, (_Float16)1, (_Float16)1,
                   (_Float16)1, (_Float16)1, (_Float16)1, (_Float16)1};
    f32x4 b1v[4], w2v[4];                  // C row = mt*16 + quad*4 + r
    #pragma unroll
    for (int mt = 0; mt < 4; ++mt) {
        const float4 bb = *(const float4*)(b1 + mt * 16 + quad * 4);
        const float4 ww = *(const float4*)(w2 + mt * 16 + quad * 4);
        b1v[mt] = (f32x4){bb.x, bb.y, bb.z, bb.w};
        w2v[mt] = (f32x4){ww.x, ww.y, ww.z, ww.w};
    }
    __syncthreads();

    // ---- main loop: interleaved gi across the 4 waves (28/24/21/18 tiles) ----
    const int a4 = n16 >> 2, b4 = n16 & 3;
    float se = 0.f, sei = 0.f;

    for (int gi = wid; gi < NG; gi += 4) {
        const int i = gi * 4 + a4;
        const _Float16* ri = fach + (size_t)i * FROW + quad * 8;
        const h16x8 ri0 = *(const h16x8*)(ri);        // i-row register-cached per gi
        const h16x8 ri1 = *(const h16x8*)(ri + 32);

        const _Float16* rjp = fach + (size_t)(gi * 4 + b4) * FROW + quad * 8;
        h16x8 nj0 = *(const h16x8*)(rjp);             // prefetched j-row
        h16x8 nj1 = *(const h16x8*)(rjp + 32);

        for (int gj = gi; gj < NG; ++gj) {
            h16x8 rj0 = nj0, rj1 = nj1;
            if (gj + 1 < NG) {                         // prefetch next tile's j-row
                rjp += 4 * FROW;
                nj0 = *(const h16x8*)(rjp);
                nj1 = *(const h16x8*)(rjp + 32);
            }
            h16x8 pr0 = ri0 * rj0;                    // 8x v_pk_mul_f16
            h16x8 pr1 = ri1 * rj1;

            f32x4 accS = __builtin_amdgcn_mfma_f32_16x16x32_f16(aones, pr0, (f32x4){0.f, 0.f, 0.f, 0.f}, 0, 0, 0);
            accS = __builtin_amdgcn_mfma_f32_16x16x32_f16(aones, pr1, accS, 0, 0, 0);
            // all lanes: accS[0] = inter_sum of pair-column n16

            float lp[4];                               // 4 independent partials
            #pragma unroll
            for (int mt = 0; mt < 4; ++mt) {
                f32x4 acc = __builtin_amdgcn_mfma_f32_16x16x32_f16(afragW[mt * 2 + 0], pr0, b1v[mt], 0, 0, 0);
                acc = __builtin_amdgcn_mfma_f32_16x16x32_f16(afragW[mt * 2 + 1], pr1, acc, 0, 0, 0);
                float s0 = fmaxf(acc[0], 0.f) * w2v[mt][0] + fmaxf(acc[1], 0.f) * w2v[mt][1];
                float s1 = fmaxf(acc[2], 0.f) * w2v[mt][2] + fmaxf(acc[3], 0.f) * w2v[mt][3];
                lp[mt] = s0 + s1;
            }
            float lacc = (lp[0] + lp[1]) + (lp[2] + lp[3]);
            lacc += __shfl_xor(lacc, 16, 64);          // att rows live across quads
            lacc += __shfl_xor(lacc, 32, 64);

            const int j = gj * 4 + b4;
            const bool valid = (i < j) && (j < NF);
            float e = valid ? __expf(lacc) : 0.f;      // logits O(1): no max needed
            se  += e;
            sei += e * accS[0];
        }
    }

    // reduce over the 16 pair-residues (quads hold identical copies — don't sum them)
    #pragma unroll
    for (int d = 1; d <= 8; d <<= 1) {
        se  += __shfl_xor(se, d, 64);
        sei += __shfl_xor(sei, d, 64);
    }
    if (wid == 3) {                                    // lin_w loads long since landed
        #pragma unroll
        for (int d = 1; d <= 32; d <<= 1) linv += __shfl_xor(linv, d, 64);
        if (lane == 0) s_lin = linv;
    }
    if (lane == 0) { cmb[wid][0] = se; cmb[wid][1] = sei; }
    __syncthreads();
    if (tid == 0) {
        float tse  = (cmb[0][0] + cmb[1][0]) + (cmb[2][0] + cmb[3][0]);
        float tsei = (cmb[0][1] + cmb[1][1]) + (cmb[2][1] + cmb[3][1]);
        out[b] = s_lin + lin_b[0] + tsei / tse;
    }
}

extern "C" void kernel_launch(void* const* d_in, const int* in_sizes, int n_in,
                              void* d_out, int out_size, void* d_ws, size_t ws_size,
                              hipStream_t stream) {
    const int*   x     = (const int*)d_in[0];
    const float* emb   = (const float*)d_in[1];
    const float* W1    = (const float*)d_in[2];
    const float* b1    = (const float*)d_in[3];
    const float* w2    = (const float*)d_in[4];
    // d_in[5] = b2 : constant shift on logits, cancels in softmax
    const float* lin_w = (const float*)d_in[6];
    const float* lin_b = (const float*)d_in[7];
    float* out = (float*)d_out;

    _Float16* w1f = (_Float16*)d_ws;
    afm_pre<<<2, 256, 0, stream>>>(W1, w1f);
    const int batch = out_size; // 2048
    afm_main<<<batch, 256, 0, stream>>>(x, emb, b1, w2, lin_w, lin_b, w1f, out);
}